// Round 16
// baseline (128.230 us; speedup 1.0000x reference)
//
#include <hip/hip_runtime.h>
#include <hip/hip_bf16.h>

#define ROWS 1025   // B*N + 1
#define DD   128    // D
#define C3   384    // 3*D
#define BB   8
#define NN   128

#define NL2E  (-1.4426950408889634f)   // -log2(e)

typedef __attribute__((ext_vector_type(8))) short short8x;
typedef __attribute__((ext_vector_type(4))) float float4x;

__device__ __forceinline__ unsigned short f2bf(float f) {
    unsigned int i = __float_as_uint(f);            // finite data only
    return (unsigned short)((i + 0x7FFFu + ((i >> 16) & 1u)) >> 16);
}
__device__ __forceinline__ unsigned int pk_bf16(float lo, float hi) {
    unsigned int r;
    asm("v_cvt_pk_bf16_f32 %0, %1, %2" : "=v"(r) : "v"(lo), "v"(hi));
    return r;
}

// MFMA gate-table GEMM  [R14 verbatim]
__global__ __launch_bounds__(256) void gtab_kernel(
    const float* __restrict__ h,
    const float* __restrict__ Wi, const float* __restrict__ Wh,   // [384][128]
    const float* __restrict__ bi, const float* __restrict__ bh,
    unsigned short* __restrict__ GiP, unsigned short* __restrict__ GhP) {
    __shared__ unsigned short hsB[16][136];   // bf16 A-tile, +16B row pad
    const int t  = threadIdx.x;
    const int rt = blockIdx.x >> 2, cg = blockIdx.x & 3;
    const int r0 = rt * 16;

    {
        const int row  = t >> 4;               // 0..15
        const int k0   = (t & 15) * 8;         // 0..120
        const float* hp = h + (size_t)min(r0 + row, ROWS - 1) * DD + k0;
        const float4 f0 = *reinterpret_cast<const float4*>(hp);
        const float4 f1 = *reinterpret_cast<const float4*>(hp + 4);
        uint4 p;
        p.x = pk_bf16(f0.x, f0.y); p.y = pk_bf16(f0.z, f0.w);
        p.z = pk_bf16(f1.x, f1.y); p.w = pk_bf16(f1.z, f1.w);
        *reinterpret_cast<uint4*>(&hsB[row][k0]) = p;
    }
    if (cg == 0) {
        for (int idx = t; idx < 16 * DD; idx += 256) {
            const int row = r0 + (idx >> 7), d = idx & (DD - 1);
            if (row < ROWS)
                GhP[(size_t)row * 512 + d * 4 + 3] = f2bf(h[(size_t)row * DD + d]);
        }
    }
    __syncthreads();

    const int wv = t >> 6, l = t & 63;
    const int lcol = l & 15, lk = l >> 4;      // col-in-tile, k-group

    short8x afrag[4];
#pragma unroll
    for (int ks = 0; ks < 4; ++ks)
        afrag[ks] = *reinterpret_cast<const short8x*>(&hsB[lcol][ks * 32 + lk * 8]);

#pragma unroll
    for (int ct = 0; ct < 3; ++ct) {
        const int  cc2 = cg * 192 + wv * 48 + ct * 16 + lcol;   // 0..767
        const bool isI = cc2 < C3;
        const int  cc  = isI ? cc2 : cc2 - C3;
        const float* __restrict__ W = isI ? Wi : Wh;
        float4x acc = {0.f, 0.f, 0.f, 0.f};
#pragma unroll
        for (int ks = 0; ks < 4; ++ks) {
            const float* wp = W + (size_t)cc * DD + ks * 32 + lk * 8;
            const float4 g0 = *reinterpret_cast<const float4*>(wp);
            const float4 g1 = *reinterpret_cast<const float4*>(wp + 4);
            union { unsigned int u[4]; short8x s; } bu;
            bu.u[0] = pk_bf16(g0.x, g0.y); bu.u[1] = pk_bf16(g0.z, g0.w);
            bu.u[2] = pk_bf16(g1.x, g1.y); bu.u[3] = pk_bf16(g1.z, g1.w);
            acc = __builtin_amdgcn_mfma_f32_16x16x32_bf16(afrag[ks], bu.s, acc, 0, 0, 0);
        }
        const int   gate  = cc >> 7, d = cc & (DD - 1);
        const float scale = (gate == 2) ? 2.0f * NL2E : NL2E;
        const float bv    = (isI ? bi : bh)[cc];
        unsigned short* __restrict__ G = isI ? GiP : GhP;
#pragma unroll
        for (int r = 0; r < 4; ++r) {
            const int row = r0 + lk * 4 + r;
            if (row < ROWS)
                G[(size_t)row * 512 + d * 4 + gate] = f2bf((acc[r] + bv) * scale);
        }
    }
}

// Phase kernel  [R15 verbatim]
template<int XC, int WRITE_OUT>
__global__ __launch_bounds__(512, 4) void phase_kernel(
    const float* __restrict__ hin,
    const int* __restrict__ parent, const int* __restrict__ child,
    const unsigned short* __restrict__ GiP, const unsigned short* __restrict__ GhP,
    float* __restrict__ hout,
    const int* __restrict__ tgt, float* __restrict__ out) {
    const int bj = blockIdx.x;          // 0..1023
    const int t  = threadIdx.x;
    const int b  = bj >> 7, j = bj & (NN - 1);
    const size_t base = (size_t)b * NN * NN + j;          // + i*NN

    __shared__ int   pcs[2 * NN];       // interleaved {p,c} pairs
    __shared__ float sacc[8][DD];       // 4 KB
    if (t < NN)            pcs[2 * t]            = parent[base + (size_t)t * NN];
    else if (t < 2 * NN)   pcs[2 * (t - NN) + 1] = child [base + (size_t)(t - NN) * NN];
    __syncthreads();

    const int w = t >> 6, l = t & 63;
    const int d0 = l * 2;               // d-pair (d0, d0+1)
    float acc0 = 0.0f, acc1 = 0.0f;
#pragma unroll 4
    for (int it = 0; it < 16; ++it) {
        const int  i  = w + it * 8;
        const int2 pc = *reinterpret_cast<const int2*>(&pcs[2 * i]);
        const int  xi = XC ? pc.y : pc.x;
        const int  hi = XC ? pc.x : pc.y;
        const uint4 ux = *reinterpret_cast<const uint4*>(GiP + (size_t)xi * 512 + d0 * 4);
        const uint4 uh = *reinterpret_cast<const uint4*>(GhP + (size_t)hi * 512 + d0 * 4);
        {
            const float irs = __uint_as_float(ux.x << 16);
            const float izs = __uint_as_float(ux.x & 0xffff0000u);
            const float ins = __uint_as_float(ux.y << 16);
            const float hrs = __uint_as_float(uh.x << 16);
            const float hzs = __uint_as_float(uh.x & 0xffff0000u);
            const float hns = __uint_as_float(uh.y << 16);
            const float hv  = __uint_as_float(uh.y & 0xffff0000u);
            const float r = __builtin_amdgcn_rcpf(1.0f + __builtin_amdgcn_exp2f(irs + hrs));
            const float z = __builtin_amdgcn_rcpf(1.0f + __builtin_amdgcn_exp2f(izs + hzs));
            const float q = __builtin_amdgcn_rcpf(1.0f + __builtin_amdgcn_exp2f(ins + r * hns));
            const float n = 2.0f * q - 1.0f;
            acc0 += n + z * (hv - n);
        }
        {
            const float irs = __uint_as_float(ux.z << 16);
            const float izs = __uint_as_float(ux.z & 0xffff0000u);
            const float ins = __uint_as_float(ux.w << 16);
            const float hrs = __uint_as_float(uh.z << 16);
            const float hzs = __uint_as_float(uh.z & 0xffff0000u);
            const float hns = __uint_as_float(uh.w << 16);
            const float hv  = __uint_as_float(uh.w & 0xffff0000u);
            const float r = __builtin_amdgcn_rcpf(1.0f + __builtin_amdgcn_exp2f(irs + hrs));
            const float z = __builtin_amdgcn_rcpf(1.0f + __builtin_amdgcn_exp2f(izs + hzs));
            const float q = __builtin_amdgcn_rcpf(1.0f + __builtin_amdgcn_exp2f(ins + r * hns));
            const float n = 2.0f * q - 1.0f;
            acc1 += n + z * (hv - n);
        }
    }
    sacc[w][d0] = acc0;
    sacc[w][d0 + 1] = acc1;
    __syncthreads();

    if (t < DD) {
        const int d = t;
        float v = sacc[0][d];
#pragma unroll
        for (int ww = 1; ww < 8; ++ww) v += sacc[ww][d];
        const int   row = 1 + bj;
        const float res = hin[(size_t)row * DD + d] + v;
        if (WRITE_OUT) {
#pragma unroll
            for (int bb = 0; bb < BB; ++bb)
                if (tgt[bb] == row) out[bb * DD + d] = res;
        } else {
            hout[(size_t)row * DD + d] = res;
        }
    } else if (t < 2 * DD && bj == 0 && !WRITE_OUT) {
        hout[t - DD] = hin[t - DD];       // row 0 unchanged (tgt >= 1 always)
    }
}

extern "C" void kernel_launch(void* const* d_in, const int* in_sizes, int n_in,
                              void* d_out, int out_size, void* d_ws, size_t ws_size,
                              hipStream_t stream) {
    const float* hidden = (const float*)d_in[0];
    const int*   parent = (const int*)d_in[1];
    const int*   child  = (const int*)d_in[2];
    const int*   tgt    = (const int*)d_in[3];
    const float* Wif    = (const float*)d_in[4];
    const float* Whf    = (const float*)d_in[5];
    const float* bif    = (const float*)d_in[6];
    const float* bhf    = (const float*)d_in[7];
    const float* Wib    = (const float*)d_in[8];
    const float* Whb    = (const float*)d_in[9];
    const float* bib    = (const float*)d_in[10];
    const float* bhb    = (const float*)d_in[11];

    char* ws = (char*)d_ws;
    unsigned short* GiP = (unsigned short*)(ws);                  // 1025*512 bf16
    unsigned short* GhP = (unsigned short*)(ws + 1049600);        // 1025*512 bf16
    float*          h1  = (float*)(ws + 2099200);                 // 1025*128 f32
    float*          out = (float*)d_out;

    // === INSTRUMENTATION: phases launched 3x (pure functions of their inputs;
    // identical output). p = (dur - 61.1)/4. gtab/phase code R15-verbatim. ===
    gtab_kernel<<<260, 256, 0, stream>>>(hidden, Wib, Whb, bib, bhb, GiP, GhP);
    phase_kernel<1, 0><<<BB * NN, 512, 0, stream>>>(hidden, parent, child, GiP, GhP, h1, nullptr, nullptr);
    phase_kernel<1, 0><<<BB * NN, 512, 0, stream>>>(hidden, parent, child, GiP, GhP, h1, nullptr, nullptr);
    phase_kernel<1, 0><<<BB * NN, 512, 0, stream>>>(hidden, parent, child, GiP, GhP, h1, nullptr, nullptr);
    gtab_kernel<<<260, 256, 0, stream>>>(h1, Wif, Whf, bif, bhf, GiP, GhP);
    phase_kernel<0, 1><<<BB * NN, 512, 0, stream>>>(h1, parent, child, GiP, GhP, nullptr, tgt, out);
    phase_kernel<0, 1><<<BB * NN, 512, 0, stream>>>(h1, parent, child, GiP, GhP, nullptr, tgt, out);
    phase_kernel<0, 1><<<BB * NN, 512, 0, stream>>>(h1, parent, child, GiP, GhP, nullptr, tgt, out);
}

// Round 17
// 59.272 us; speedup vs baseline: 2.1634x; 2.1634x over previous
//
#include <hip/hip_runtime.h>
#include <hip/hip_bf16.h>

#define ROWS 1025   // B*N + 1
#define DD   128    // D
#define C3   384    // 3*D
#define BB   8
#define NN   128

#define NL2E  (-1.4426950408889634f)   // -log2(e)

typedef __attribute__((ext_vector_type(8))) short short8x;
typedef __attribute__((ext_vector_type(4))) float float4x;

__device__ __forceinline__ unsigned short f2bf(float f) {
    unsigned int i = __float_as_uint(f);            // finite data only
    return (unsigned short)((i + 0x7FFFu + ((i >> 16) & 1u)) >> 16);
}
__device__ __forceinline__ unsigned int pk_bf16(float lo, float hi) {
    unsigned int r;
    asm("v_cvt_pk_bf16_f32 %0, %1, %2" : "=v"(r) : "v"(lo), "v"(hi));
    return r;
}

// MFMA gate-table GEMM, occupancy-fixed: 65 row-tiles x 12 col-groups(64) =
// 780 blocks x 256 thr (4 waves); wave = ONE 16-col tile, K=128 via 4 MFMA.
// ~3 blocks/CU -> 3 waves/SIMD (vs 1 in R14) to cover W-load latency.
//   GiP[row][d] = {-L*ir, -L*iz, -2L*in, (unused)}
//   GhP[row][d] = {-L*hr, -L*hz, -2L*hn, h}
__global__ __launch_bounds__(256) void gtab_kernel(
    const float* __restrict__ h,
    const float* __restrict__ Wi, const float* __restrict__ Wh,   // [384][128]
    const float* __restrict__ bi, const float* __restrict__ bh,
    unsigned short* __restrict__ GiP, unsigned short* __restrict__ GhP) {
    __shared__ unsigned short hsB[16][136];   // bf16 A-tile, +16B row pad
    const int t  = threadIdx.x;
    const int rt = blockIdx.x / 12, cg = blockIdx.x % 12;
    const int r0 = rt * 16;

    {
        const int row  = t >> 4;               // 0..15
        const int k0   = (t & 15) * 8;         // 0..120
        const float* hp = h + (size_t)min(r0 + row, ROWS - 1) * DD + k0;
        const float4 f0 = *reinterpret_cast<const float4*>(hp);
        const float4 f1 = *reinterpret_cast<const float4*>(hp + 4);
        uint4 p;
        p.x = pk_bf16(f0.x, f0.y); p.y = pk_bf16(f0.z, f0.w);
        p.z = pk_bf16(f1.x, f1.y); p.w = pk_bf16(f1.z, f1.w);
        *reinterpret_cast<uint4*>(&hsB[row][k0]) = p;
    }
    if (cg == 0) {
        for (int idx = t; idx < 16 * DD; idx += 256) {
            const int row = r0 + (idx >> 7), d = idx & (DD - 1);
            if (row < ROWS)
                GhP[(size_t)row * 512 + d * 4 + 3] = f2bf(h[(size_t)row * DD + d]);
        }
    }
    __syncthreads();

    const int wv = t >> 6, l = t & 63;
    const int lcol = l & 15, lk = l >> 4;      // col-in-tile, k-group

    short8x afrag[4];
#pragma unroll
    for (int ks = 0; ks < 4; ++ks)
        afrag[ks] = *reinterpret_cast<const short8x*>(&hsB[lcol][ks * 32 + lk * 8]);

    const int  cc2 = cg * 64 + wv * 16 + lcol;     // 0..767
    const bool isI = cc2 < C3;
    const int  cc  = isI ? cc2 : cc2 - C3;
    const float* __restrict__ W = isI ? Wi : Wh;
    float4x acc = {0.f, 0.f, 0.f, 0.f};
#pragma unroll
    for (int ks = 0; ks < 4; ++ks) {
        const float* wp = W + (size_t)cc * DD + ks * 32 + lk * 8;
        const float4 g0 = *reinterpret_cast<const float4*>(wp);
        const float4 g1 = *reinterpret_cast<const float4*>(wp + 4);
        union { unsigned int u[4]; short8x s; } bu;
        bu.u[0] = pk_bf16(g0.x, g0.y); bu.u[1] = pk_bf16(g0.z, g0.w);
        bu.u[2] = pk_bf16(g1.x, g1.y); bu.u[3] = pk_bf16(g1.z, g1.w);
        acc = __builtin_amdgcn_mfma_f32_16x16x32_bf16(afrag[ks], bu.s, acc, 0, 0, 0);
    }
    // Epilogue: C layout col=lane&15, row=(lane>>4)*4+reg  [m89-verified]
    const int   gate  = cc >> 7, d = cc & (DD - 1);
    const float scale = (gate == 2) ? 2.0f * NL2E : NL2E;
    const float bv    = (isI ? bi : bh)[cc];
    unsigned short* __restrict__ G = isI ? GiP : GhP;
#pragma unroll
    for (int r = 0; r < 4; ++r) {
        const int row = r0 + lk * 4 + r;
        if (row < ROWS)
            G[(size_t)row * 512 + d * 4 + gate] = f2bf((acc[r] + bv) * scale);
    }
}

// Phase kernel  [R15 verbatim]
template<int XC, int WRITE_OUT>
__global__ __launch_bounds__(512, 4) void phase_kernel(
    const float* __restrict__ hin,
    const int* __restrict__ parent, const int* __restrict__ child,
    const unsigned short* __restrict__ GiP, const unsigned short* __restrict__ GhP,
    float* __restrict__ hout,
    const int* __restrict__ tgt, float* __restrict__ out) {
    const int bj = blockIdx.x;          // 0..1023
    const int t  = threadIdx.x;
    const int b  = bj >> 7, j = bj & (NN - 1);
    const size_t base = (size_t)b * NN * NN + j;          // + i*NN

    __shared__ int   pcs[2 * NN];       // interleaved {p,c} pairs
    __shared__ float sacc[8][DD];       // 4 KB
    if (t < NN)            pcs[2 * t]            = parent[base + (size_t)t * NN];
    else if (t < 2 * NN)   pcs[2 * (t - NN) + 1] = child [base + (size_t)(t - NN) * NN];
    __syncthreads();

    const int w = t >> 6, l = t & 63;
    const int d0 = l * 2;               // d-pair (d0, d0+1)
    float acc0 = 0.0f, acc1 = 0.0f;
#pragma unroll 4
    for (int it = 0; it < 16; ++it) {
        const int  i  = w + it * 8;
        const int2 pc = *reinterpret_cast<const int2*>(&pcs[2 * i]);
        const int  xi = XC ? pc.y : pc.x;
        const int  hi = XC ? pc.x : pc.y;
        const uint4 ux = *reinterpret_cast<const uint4*>(GiP + (size_t)xi * 512 + d0 * 4);
        const uint4 uh = *reinterpret_cast<const uint4*>(GhP + (size_t)hi * 512 + d0 * 4);
        {
            const float irs = __uint_as_float(ux.x << 16);
            const float izs = __uint_as_float(ux.x & 0xffff0000u);
            const float ins = __uint_as_float(ux.y << 16);
            const float hrs = __uint_as_float(uh.x << 16);
            const float hzs = __uint_as_float(uh.x & 0xffff0000u);
            const float hns = __uint_as_float(uh.y << 16);
            const float hv  = __uint_as_float(uh.y & 0xffff0000u);
            const float r = __builtin_amdgcn_rcpf(1.0f + __builtin_amdgcn_exp2f(irs + hrs));
            const float z = __builtin_amdgcn_rcpf(1.0f + __builtin_amdgcn_exp2f(izs + hzs));
            const float q = __builtin_amdgcn_rcpf(1.0f + __builtin_amdgcn_exp2f(ins + r * hns));
            const float n = 2.0f * q - 1.0f;
            acc0 += n + z * (hv - n);
        }
        {
            const float irs = __uint_as_float(ux.z << 16);
            const float izs = __uint_as_float(ux.z & 0xffff0000u);
            const float ins = __uint_as_float(ux.w << 16);
            const float hrs = __uint_as_float(uh.z << 16);
            const float hzs = __uint_as_float(uh.z & 0xffff0000u);
            const float hns = __uint_as_float(uh.w << 16);
            const float hv  = __uint_as_float(uh.w & 0xffff0000u);
            const float r = __builtin_amdgcn_rcpf(1.0f + __builtin_amdgcn_exp2f(irs + hrs));
            const float z = __builtin_amdgcn_rcpf(1.0f + __builtin_amdgcn_exp2f(izs + hzs));
            const float q = __builtin_amdgcn_rcpf(1.0f + __builtin_amdgcn_exp2f(ins + r * hns));
            const float n = 2.0f * q - 1.0f;
            acc1 += n + z * (hv - n);
        }
    }
    sacc[w][d0] = acc0;
    sacc[w][d0 + 1] = acc1;
    __syncthreads();

    if (t < DD) {
        const int d = t;
        float v = sacc[0][d];
#pragma unroll
        for (int ww = 1; ww < 8; ++ww) v += sacc[ww][d];
        const int   row = 1 + bj;
        const float res = hin[(size_t)row * DD + d] + v;
        if (WRITE_OUT) {
#pragma unroll
            for (int bb = 0; bb < BB; ++bb)
                if (tgt[bb] == row) out[bb * DD + d] = res;
        } else {
            hout[(size_t)row * DD + d] = res;
        }
    } else if (t < 2 * DD && bj == 0 && !WRITE_OUT) {
        hout[t - DD] = hin[t - DD];       // row 0 unchanged (tgt >= 1 always)
    }
}

extern "C" void kernel_launch(void* const* d_in, const int* in_sizes, int n_in,
                              void* d_out, int out_size, void* d_ws, size_t ws_size,
                              hipStream_t stream) {
    const float* hidden = (const float*)d_in[0];
    const int*   parent = (const int*)d_in[1];
    const int*   child  = (const int*)d_in[2];
    const int*   tgt    = (const int*)d_in[3];
    const float* Wif    = (const float*)d_in[4];
    const float* Whf    = (const float*)d_in[5];
    const float* bif    = (const float*)d_in[6];
    const float* bhf    = (const float*)d_in[7];
    const float* Wib    = (const float*)d_in[8];
    const float* Whb    = (const float*)d_in[9];
    const float* bib    = (const float*)d_in[10];
    const float* bhb    = (const float*)d_in[11];

    char* ws = (char*)d_ws;
    unsigned short* GiP = (unsigned short*)(ws);                  // 1025*512 bf16
    unsigned short* GhP = (unsigned short*)(ws + 1049600);        // 1025*512 bf16
    float*          h1  = (float*)(ws + 2099200);                 // 1025*128 f32
    float*          out = (float*)d_out;

    // Phase 1: bwd weights, x = child, h = parent
    gtab_kernel<<<780, 256, 0, stream>>>(hidden, Wib, Whb, bib, bhb, GiP, GhP);
    phase_kernel<1, 0><<<BB * NN, 512, 0, stream>>>(hidden, parent, child, GiP, GhP, h1, nullptr, nullptr);
    // Phase 2: fwd weights, x = parent, h = child; tgt gather fused
    gtab_kernel<<<780, 256, 0, stream>>>(h1, Wif, Whf, bif, bhf, GiP, GhP);
    phase_kernel<0, 1><<<BB * NN, 512, 0, stream>>>(h1, parent, child, GiP, GhP, nullptr, tgt, out);
}

// Round 18
// 56.514 us; speedup vs baseline: 2.2690x; 1.0488x over previous
//
#include <hip/hip_runtime.h>
#include <hip/hip_bf16.h>

#define ROWS 1025   // B*N + 1
#define DD   128    // D
#define C3   384    // 3*D
#define BB   8
#define NN   128

#define NL2E  (-1.4426950408889634f)   // -log2(e)

typedef __attribute__((ext_vector_type(8))) short short8x;
typedef __attribute__((ext_vector_type(4))) float float4x;

__device__ __forceinline__ unsigned short f2bf(float f) {
    unsigned int i = __float_as_uint(f);            // finite data only
    return (unsigned short)((i + 0x7FFFu + ((i >> 16) & 1u)) >> 16);
}
__device__ __forceinline__ unsigned int pk_bf16(float lo, float hi) {
    unsigned int r;
    asm("v_cvt_pk_bf16_f32 %0, %1, %2" : "=v"(r) : "v"(lo), "v"(hi));
    return r;
}
// Non-temporal store: intermediates are consumed by OTHER XCDs next kernel;
// streaming past the writer's L2 avoids the dirty-remote coherence round-trip.
__device__ __forceinline__ void nt_store(unsigned short* p, unsigned short v) {
    __builtin_nontemporal_store(v, p);
}
__device__ __forceinline__ void nt_store(float* p, float v) {
    __builtin_nontemporal_store(v, p);
}

// MFMA gate-table GEMM  [R17 structure; nt stores]
//   GiP[row][d] = {-L*ir, -L*iz, -2L*in, (unused)}
//   GhP[row][d] = {-L*hr, -L*hz, -2L*hn, h}
// 65 row-tiles x 12 col-groups(64) = 780 blocks x 256 thr; wave = one 16-col
// tile, K=128 via 4 x mfma_f32_16x16x32_bf16.
__global__ __launch_bounds__(256) void gtab_kernel(
    const float* __restrict__ h,
    const float* __restrict__ Wi, const float* __restrict__ Wh,   // [384][128]
    const float* __restrict__ bi, const float* __restrict__ bh,
    unsigned short* __restrict__ GiP, unsigned short* __restrict__ GhP) {
    __shared__ unsigned short hsB[16][136];   // bf16 A-tile, +16B row pad
    const int t  = threadIdx.x;
    const int rt = blockIdx.x / 12, cg = blockIdx.x % 12;
    const int r0 = rt * 16;

    {
        const int row  = t >> 4;               // 0..15
        const int k0   = (t & 15) * 8;         // 0..120
        const float* hp = h + (size_t)min(r0 + row, ROWS - 1) * DD + k0;
        const float4 f0 = *reinterpret_cast<const float4*>(hp);
        const float4 f1 = *reinterpret_cast<const float4*>(hp + 4);
        uint4 p;
        p.x = pk_bf16(f0.x, f0.y); p.y = pk_bf16(f0.z, f0.w);
        p.z = pk_bf16(f1.x, f1.y); p.w = pk_bf16(f1.z, f1.w);
        *reinterpret_cast<uint4*>(&hsB[row][k0]) = p;
    }
    if (cg == 0) {
        for (int idx = t; idx < 16 * DD; idx += 256) {
            const int row = r0 + (idx >> 7), d = idx & (DD - 1);
            if (row < ROWS)
                nt_store(&GhP[(size_t)row * 512 + d * 4 + 3],
                         f2bf(h[(size_t)row * DD + d]));
        }
    }
    __syncthreads();

    const int wv = t >> 6, l = t & 63;
    const int lcol = l & 15, lk = l >> 4;      // col-in-tile, k-group

    short8x afrag[4];
#pragma unroll
    for (int ks = 0; ks < 4; ++ks)
        afrag[ks] = *reinterpret_cast<const short8x*>(&hsB[lcol][ks * 32 + lk * 8]);

    const int  cc2 = cg * 64 + wv * 16 + lcol;     // 0..767
    const bool isI = cc2 < C3;
    const int  cc  = isI ? cc2 : cc2 - C3;
    const float* __restrict__ W = isI ? Wi : Wh;
    float4x acc = {0.f, 0.f, 0.f, 0.f};
#pragma unroll
    for (int ks = 0; ks < 4; ++ks) {
        const float* wp = W + (size_t)cc * DD + ks * 32 + lk * 8;
        const float4 g0 = *reinterpret_cast<const float4*>(wp);
        const float4 g1 = *reinterpret_cast<const float4*>(wp + 4);
        union { unsigned int u[4]; short8x s; } bu;
        bu.u[0] = pk_bf16(g0.x, g0.y); bu.u[1] = pk_bf16(g0.z, g0.w);
        bu.u[2] = pk_bf16(g1.x, g1.y); bu.u[3] = pk_bf16(g1.z, g1.w);
        acc = __builtin_amdgcn_mfma_f32_16x16x32_bf16(afrag[ks], bu.s, acc, 0, 0, 0);
    }
    // Epilogue: C layout col=lane&15, row=(lane>>4)*4+reg  [m89-verified]
    const int   gate  = cc >> 7, d = cc & (DD - 1);
    const float scale = (gate == 2) ? 2.0f * NL2E : NL2E;
    const float bv    = (isI ? bi : bh)[cc];
    unsigned short* __restrict__ G = isI ? GiP : GhP;
#pragma unroll
    for (int r = 0; r < 4; ++r) {
        const int row = r0 + lk * 4 + r;
        if (row < ROWS)
            nt_store(&G[(size_t)row * 512 + d * 4 + gate],
                     f2bf((acc[r] + bv) * scale));
    }
}

// Phase kernel  [R15 verbatim; nt stores on h1/row-0]
template<int XC, int WRITE_OUT>
__global__ __launch_bounds__(512, 4) void phase_kernel(
    const float* __restrict__ hin,
    const int* __restrict__ parent, const int* __restrict__ child,
    const unsigned short* __restrict__ GiP, const unsigned short* __restrict__ GhP,
    float* __restrict__ hout,
    const int* __restrict__ tgt, float* __restrict__ out) {
    const int bj = blockIdx.x;          // 0..1023
    const int t  = threadIdx.x;
    const int b  = bj >> 7, j = bj & (NN - 1);
    const size_t base = (size_t)b * NN * NN + j;          // + i*NN

    __shared__ int   pcs[2 * NN];       // interleaved {p,c} pairs
    __shared__ float sacc[8][DD];       // 4 KB
    if (t < NN)            pcs[2 * t]            = parent[base + (size_t)t * NN];
    else if (t < 2 * NN)   pcs[2 * (t - NN) + 1] = child [base + (size_t)(t - NN) * NN];
    __syncthreads();

    const int w = t >> 6, l = t & 63;
    const int d0 = l * 2;               // d-pair (d0, d0+1)
    float acc0 = 0.0f, acc1 = 0.0f;
#pragma unroll 4
    for (int it = 0; it < 16; ++it) {
        const int  i  = w + it * 8;
        const int2 pc = *reinterpret_cast<const int2*>(&pcs[2 * i]);
        const int  xi = XC ? pc.y : pc.x;
        const int  hi = XC ? pc.x : pc.y;
        const uint4 ux = *reinterpret_cast<const uint4*>(GiP + (size_t)xi * 512 + d0 * 4);
        const uint4 uh = *reinterpret_cast<const uint4*>(GhP + (size_t)hi * 512 + d0 * 4);
        {
            const float irs = __uint_as_float(ux.x << 16);
            const float izs = __uint_as_float(ux.x & 0xffff0000u);
            const float ins = __uint_as_float(ux.y << 16);
            const float hrs = __uint_as_float(uh.x << 16);
            const float hzs = __uint_as_float(uh.x & 0xffff0000u);
            const float hns = __uint_as_float(uh.y << 16);
            const float hv  = __uint_as_float(uh.y & 0xffff0000u);
            const float r = __builtin_amdgcn_rcpf(1.0f + __builtin_amdgcn_exp2f(irs + hrs));
            const float z = __builtin_amdgcn_rcpf(1.0f + __builtin_amdgcn_exp2f(izs + hzs));
            const float q = __builtin_amdgcn_rcpf(1.0f + __builtin_amdgcn_exp2f(ins + r * hns));
            const float n = 2.0f * q - 1.0f;
            acc0 += n + z * (hv - n);
        }
        {
            const float irs = __uint_as_float(ux.z << 16);
            const float izs = __uint_as_float(ux.z & 0xffff0000u);
            const float ins = __uint_as_float(ux.w << 16);
            const float hrs = __uint_as_float(uh.z << 16);
            const float hzs = __uint_as_float(uh.z & 0xffff0000u);
            const float hns = __uint_as_float(uh.w << 16);
            const float hv  = __uint_as_float(uh.w & 0xffff0000u);
            const float r = __builtin_amdgcn_rcpf(1.0f + __builtin_amdgcn_exp2f(irs + hrs));
            const float z = __builtin_amdgcn_rcpf(1.0f + __builtin_amdgcn_exp2f(izs + hzs));
            const float q = __builtin_amdgcn_rcpf(1.0f + __builtin_amdgcn_exp2f(ins + r * hns));
            const float n = 2.0f * q - 1.0f;
            acc1 += n + z * (hv - n);
        }
    }
    sacc[w][d0] = acc0;
    sacc[w][d0 + 1] = acc1;
    __syncthreads();

    if (t < DD) {
        const int d = t;
        float v = sacc[0][d];
#pragma unroll
        for (int ww = 1; ww < 8; ++ww) v += sacc[ww][d];
        const int   row = 1 + bj;
        const float res = hin[(size_t)row * DD + d] + v;
        if (WRITE_OUT) {
#pragma unroll
            for (int bb = 0; bb < BB; ++bb)
                if (tgt[bb] == row) out[bb * DD + d] = res;
        } else {
            nt_store(&hout[(size_t)row * DD + d], res);   // read cross-XCD by gtab2
        }
    } else if (t < 2 * DD && bj == 0 && !WRITE_OUT) {
        nt_store(&hout[t - DD], hin[t - DD]);   // row 0 unchanged (tgt >= 1)
    }
}

extern "C" void kernel_launch(void* const* d_in, const int* in_sizes, int n_in,
                              void* d_out, int out_size, void* d_ws, size_t ws_size,
                              hipStream_t stream) {
    const float* hidden = (const float*)d_in[0];
    const int*   parent = (const int*)d_in[1];
    const int*   child  = (const int*)d_in[2];
    const int*   tgt    = (const int*)d_in[3];
    const float* Wif    = (const float*)d_in[4];
    const float* Whf    = (const float*)d_in[5];
    const float* bif    = (const float*)d_in[6];
    const float* bhf    = (const float*)d_in[7];
    const float* Wib    = (const float*)d_in[8];
    const float* Whb    = (const float*)d_in[9];
    const float* bib    = (const float*)d_in[10];
    const float* bhb    = (const float*)d_in[11];

    char* ws = (char*)d_ws;
    unsigned short* GiP = (unsigned short*)(ws);                  // 1025*512 bf16
    unsigned short* GhP = (unsigned short*)(ws + 1049600);        // 1025*512 bf16
    float*          h1  = (float*)(ws + 2099200);                 // 1025*128 f32
    float*          out = (float*)d_out;

    // Phase 1: bwd weights, x = child, h = parent
    gtab_kernel<<<780, 256, 0, stream>>>(hidden, Wib, Whb, bib, bhb, GiP, GhP);
    phase_kernel<1, 0><<<BB * NN, 512, 0, stream>>>(hidden, parent, child, GiP, GhP, h1, nullptr, nullptr);
    // Phase 2: fwd weights, x = parent, h = child; tgt gather fused
    gtab_kernel<<<780, 256, 0, stream>>>(h1, Wif, Whf, bif, bhf, GiP, GhP);
    phase_kernel<0, 1><<<BB * NN, 512, 0, stream>>>(h1, parent, child, GiP, GhP, nullptr, tgt, out);
}

// Round 19
// 51.487 us; speedup vs baseline: 2.4905x; 1.0976x over previous
//
#include <hip/hip_runtime.h>
#include <hip/hip_bf16.h>

#define ROWS 1025   // B*N + 1
#define DD   128    // D
#define C3   384    // 3*D
#define BB   8
#define NN   128

#define NL2E  (-1.4426950408889634f)   // -log2(e)

typedef __attribute__((ext_vector_type(8))) short short8x;
typedef __attribute__((ext_vector_type(4))) float float4x;

__device__ __forceinline__ unsigned short f2bf(float f) {
    unsigned int i = __float_as_uint(f);            // finite data only
    return (unsigned short)((i + 0x7FFFu + ((i >> 16) & 1u)) >> 16);
}
__device__ __forceinline__ unsigned int pk_bf16(float lo, float hi) {
    unsigned int r;
    asm("v_cvt_pk_bf16_f32 %0, %1, %2" : "=v"(r) : "v"(lo), "v"(hi));
    return r;
}
__device__ __forceinline__ void nt_store(unsigned short* p, unsigned short v) {
    __builtin_nontemporal_store(v, p);
}
__device__ __forceinline__ void nt_store(float* p, float v) {
    __builtin_nontemporal_store(v, p);
}

// MFMA gate-table GEMM  [R17 structure; nt stores; PRE-EXPONENTIATED r/z]
//   GiP[row][d] = {exp2(-L*ir), exp2(-L*iz), -2L*in, (unused)}
//   GhP[row][d] = {exp2(-L*hr), exp2(-L*hz), -2L*hn, h}
// so phase computes sigma = rcp(1 + Ei*Eh)  (mul replaces exp2).
// 65 row-tiles x 12 col-groups(64) = 780 blocks x 256 thr.
__global__ __launch_bounds__(256) void gtab_kernel(
    const float* __restrict__ h,
    const float* __restrict__ Wi, const float* __restrict__ Wh,   // [384][128]
    const float* __restrict__ bi, const float* __restrict__ bh,
    unsigned short* __restrict__ GiP, unsigned short* __restrict__ GhP) {
    __shared__ unsigned short hsB[16][136];   // bf16 A-tile, +16B row pad
    const int t  = threadIdx.x;
    const int rt = blockIdx.x / 12, cg = blockIdx.x % 12;
    const int r0 = rt * 16;

    {
        const int row  = t >> 4;               // 0..15
        const int k0   = (t & 15) * 8;         // 0..120
        const float* hp = h + (size_t)min(r0 + row, ROWS - 1) * DD + k0;
        const float4 f0 = *reinterpret_cast<const float4*>(hp);
        const float4 f1 = *reinterpret_cast<const float4*>(hp + 4);
        uint4 p;
        p.x = pk_bf16(f0.x, f0.y); p.y = pk_bf16(f0.z, f0.w);
        p.z = pk_bf16(f1.x, f1.y); p.w = pk_bf16(f1.z, f1.w);
        *reinterpret_cast<uint4*>(&hsB[row][k0]) = p;
    }
    if (cg == 0) {
        for (int idx = t; idx < 16 * DD; idx += 256) {
            const int row = r0 + (idx >> 7), d = idx & (DD - 1);
            if (row < ROWS)
                nt_store(&GhP[(size_t)row * 512 + d * 4 + 3],
                         f2bf(h[(size_t)row * DD + d]));
        }
    }
    __syncthreads();

    const int wv = t >> 6, l = t & 63;
    const int lcol = l & 15, lk = l >> 4;      // col-in-tile, k-group

    short8x afrag[4];
#pragma unroll
    for (int ks = 0; ks < 4; ++ks)
        afrag[ks] = *reinterpret_cast<const short8x*>(&hsB[lcol][ks * 32 + lk * 8]);

    const int  cc2 = cg * 64 + wv * 16 + lcol;     // 0..767
    const bool isI = cc2 < C3;
    const int  cc  = isI ? cc2 : cc2 - C3;
    const float* __restrict__ W = isI ? Wi : Wh;
    float4x acc = {0.f, 0.f, 0.f, 0.f};
#pragma unroll
    for (int ks = 0; ks < 4; ++ks) {
        const float* wp = W + (size_t)cc * DD + ks * 32 + lk * 8;
        const float4 g0 = *reinterpret_cast<const float4*>(wp);
        const float4 g1 = *reinterpret_cast<const float4*>(wp + 4);
        union { unsigned int u[4]; short8x s; } bu;
        bu.u[0] = pk_bf16(g0.x, g0.y); bu.u[1] = pk_bf16(g0.z, g0.w);
        bu.u[2] = pk_bf16(g1.x, g1.y); bu.u[3] = pk_bf16(g1.z, g1.w);
        acc = __builtin_amdgcn_mfma_f32_16x16x32_bf16(afrag[ks], bu.s, acc, 0, 0, 0);
    }
    // Epilogue: C layout col=lane&15, row=(lane>>4)*4+reg  [m89-verified]
    const int   gate  = cc >> 7, d = cc & (DD - 1);
    const float scale = (gate == 2) ? 2.0f * NL2E : NL2E;
    const float bv    = (isI ? bi : bh)[cc];
    unsigned short* __restrict__ G = isI ? GiP : GhP;
#pragma unroll
    for (int r = 0; r < 4; ++r) {
        const int row = r0 + lk * 4 + r;
        if (row < ROWS) {
            float v = (acc[r] + bv) * scale;
            if (gate != 2) v = __builtin_amdgcn_exp2f(v);   // pre-exponentiate r/z
            nt_store(&G[(size_t)row * 512 + d * 4 + gate], f2bf(v));
        }
    }
}

// Phase kernel  [R15 structure; sigma via Ei*Eh product — 4 trans/element]
template<int XC, int WRITE_OUT>
__global__ __launch_bounds__(512, 4) void phase_kernel(
    const float* __restrict__ hin,
    const int* __restrict__ parent, const int* __restrict__ child,
    const unsigned short* __restrict__ GiP, const unsigned short* __restrict__ GhP,
    float* __restrict__ hout,
    const int* __restrict__ tgt, float* __restrict__ out) {
    const int bj = blockIdx.x;          // 0..1023
    const int t  = threadIdx.x;
    const int b  = bj >> 7, j = bj & (NN - 1);
    const size_t base = (size_t)b * NN * NN + j;          // + i*NN

    __shared__ int   pcs[2 * NN];       // interleaved {p,c} pairs
    __shared__ float sacc[8][DD];       // 4 KB
    if (t < NN)            pcs[2 * t]            = parent[base + (size_t)t * NN];
    else if (t < 2 * NN)   pcs[2 * (t - NN) + 1] = child [base + (size_t)(t - NN) * NN];
    __syncthreads();

    const int w = t >> 6, l = t & 63;
    const int d0 = l * 2;               // d-pair (d0, d0+1)
    float acc0 = 0.0f, acc1 = 0.0f;
#pragma unroll 4
    for (int it = 0; it < 16; ++it) {
        const int  i  = w + it * 8;
        const int2 pc = *reinterpret_cast<const int2*>(&pcs[2 * i]);
        const int  xi = XC ? pc.y : pc.x;
        const int  hi = XC ? pc.x : pc.y;
        const uint4 ux = *reinterpret_cast<const uint4*>(GiP + (size_t)xi * 512 + d0 * 4);
        const uint4 uh = *reinterpret_cast<const uint4*>(GhP + (size_t)hi * 512 + d0 * 4);
        {
            const float Eir = __uint_as_float(ux.x << 16);
            const float Eiz = __uint_as_float(ux.x & 0xffff0000u);
            const float ins = __uint_as_float(ux.y << 16);
            const float Ehr = __uint_as_float(uh.x << 16);
            const float Ehz = __uint_as_float(uh.x & 0xffff0000u);
            const float hns = __uint_as_float(uh.y << 16);
            const float hv  = __uint_as_float(uh.y & 0xffff0000u);
            const float r = __builtin_amdgcn_rcpf(1.0f + Eir * Ehr);
            const float z = __builtin_amdgcn_rcpf(1.0f + Eiz * Ehz);
            const float q = __builtin_amdgcn_rcpf(1.0f + __builtin_amdgcn_exp2f(ins + r * hns));
            const float n = 2.0f * q - 1.0f;
            acc0 += n + z * (hv - n);
        }
        {
            const float Eir = __uint_as_float(ux.z << 16);
            const float Eiz = __uint_as_float(ux.z & 0xffff0000u);
            const float ins = __uint_as_float(ux.w << 16);
            const float Ehr = __uint_as_float(uh.z << 16);
            const float Ehz = __uint_as_float(uh.z & 0xffff0000u);
            const float hns = __uint_as_float(uh.w << 16);
            const float hv  = __uint_as_float(uh.w & 0xffff0000u);
            const float r = __builtin_amdgcn_rcpf(1.0f + Eir * Ehr);
            const float z = __builtin_amdgcn_rcpf(1.0f + Eiz * Ehz);
            const float q = __builtin_amdgcn_rcpf(1.0f + __builtin_amdgcn_exp2f(ins + r * hns));
            const float n = 2.0f * q - 1.0f;
            acc1 += n + z * (hv - n);
        }
    }
    sacc[w][d0] = acc0;
    sacc[w][d0 + 1] = acc1;
    __syncthreads();

    if (t < DD) {
        const int d = t;
        float v = sacc[0][d];
#pragma unroll
        for (int ww = 1; ww < 8; ++ww) v += sacc[ww][d];
        const int   row = 1 + bj;
        const float res = hin[(size_t)row * DD + d] + v;
        if (WRITE_OUT) {
#pragma unroll
            for (int bb = 0; bb < BB; ++bb)
                if (tgt[bb] == row) out[bb * DD + d] = res;
        } else {
            nt_store(&hout[(size_t)row * DD + d], res);   // read cross-XCD by gtab2
        }
    } else if (t < 2 * DD && bj == 0 && !WRITE_OUT) {
        nt_store(&hout[t - DD], hin[t - DD]);   // row 0 unchanged (tgt >= 1)
    }
}

extern "C" void kernel_launch(void* const* d_in, const int* in_sizes, int n_in,
                              void* d_out, int out_size, void* d_ws, size_t ws_size,
                              hipStream_t stream) {
    const float* hidden = (const float*)d_in[0];
    const int*   parent = (const int*)d_in[1];
    const int*   child  = (const int*)d_in[2];
    const int*   tgt    = (const int*)d_in[3];
    const float* Wif    = (const float*)d_in[4];
    const float* Whf    = (const float*)d_in[5];
    const float* bif    = (const float*)d_in[6];
    const float* bhf    = (const float*)d_in[7];
    const float* Wib    = (const float*)d_in[8];
    const float* Whb    = (const float*)d_in[9];
    const float* bib    = (const float*)d_in[10];
    const float* bhb    = (const float*)d_in[11];

    char* ws = (char*)d_ws;
    unsigned short* GiP = (unsigned short*)(ws);                  // 1025*512 bf16
    unsigned short* GhP = (unsigned short*)(ws + 1049600);        // 1025*512 bf16
    float*          h1  = (float*)(ws + 2099200);                 // 1025*128 f32
    float*          out = (float*)d_out;

    // Phase 1: bwd weights, x = child, h = parent
    gtab_kernel<<<780, 256, 0, stream>>>(hidden, Wib, Whb, bib, bhb, GiP, GhP);
    phase_kernel<1, 0><<<BB * NN, 512, 0, stream>>>(hidden, parent, child, GiP, GhP, h1, nullptr, nullptr);
    // Phase 2: fwd weights, x = parent, h = child; tgt gather fused
    gtab_kernel<<<780, 256, 0, stream>>>(h1, Wif, Whf, bif, bhf, GiP, GhP);
    phase_kernel<0, 1><<<BB * NN, 512, 0, stream>>>(h1, parent, child, GiP, GhP, nullptr, tgt, out);
}

// Round 20
// 51.076 us; speedup vs baseline: 2.5106x; 1.0080x over previous
//
#include <hip/hip_runtime.h>
#include <hip/hip_bf16.h>

#define ROWS 1025   // B*N + 1
#define DD   128    // D
#define C3   384    // 3*D
#define BB   8
#define NN   128

#define NL2E  (-1.4426950408889634f)   // -log2(e)

typedef __attribute__((ext_vector_type(8))) short short8x;
typedef __attribute__((ext_vector_type(4))) float float4x;

__device__ __forceinline__ unsigned short f2bf(float f) {
    unsigned int i = __float_as_uint(f);            // finite data only
    return (unsigned short)((i + 0x7FFFu + ((i >> 16) & 1u)) >> 16);
}
__device__ __forceinline__ unsigned int pk_bf16(float lo, float hi) {
    unsigned int r;
    asm("v_cvt_pk_bf16_f32 %0, %1, %2" : "=v"(r) : "v"(lo), "v"(hi));
    return r;
}
__device__ __forceinline__ void nt_store(unsigned short* p, unsigned short v) {
    __builtin_nontemporal_store(v, p);
}
__device__ __forceinline__ void nt_store(float* p, float v) {
    __builtin_nontemporal_store(v, p);
}

// MFMA gate-table GEMM, K-SPLIT-2 for occupancy:
// grid = 65 row-tiles x 24 col-groups(32) = 1560 blocks x 256 thr (4 waves).
// Wave w: colhalf=w>>1 (16-col tile), khalf=w&1 (K 0..63 / 64..127), 2 MFMAs.
// khalf=1 waves push partial acc to LDS; khalf=0 waves add + epilogue.
// 24 waves/CU (vs 12) and half-length load->MFMA chains.
//   GiP[row][d] = {exp2(-L*ir), exp2(-L*iz), -2L*in, (unused)}
//   GhP[row][d] = {exp2(-L*hr), exp2(-L*hz), -2L*hn, h}
__global__ __launch_bounds__(256) void gtab_kernel(
    const float* __restrict__ h,
    const float* __restrict__ Wi, const float* __restrict__ Wh,   // [384][128]
    const float* __restrict__ bi, const float* __restrict__ bh,
    unsigned short* __restrict__ GiP, unsigned short* __restrict__ GhP) {
    __shared__ unsigned short hsB[16][136];   // bf16 A-tile, +16B row pad
    __shared__ float sacc[2][64][4];          // khalf=1 partials, 2 KB
    const int t  = threadIdx.x;
    const int rt = blockIdx.x / 24, cg = blockIdx.x % 24;
    const int r0 = rt * 16;

    {
        const int row  = t >> 4;               // 0..15
        const int k0   = (t & 15) * 8;         // 0..120
        const float* hp = h + (size_t)min(r0 + row, ROWS - 1) * DD + k0;
        const float4 f0 = *reinterpret_cast<const float4*>(hp);
        const float4 f1 = *reinterpret_cast<const float4*>(hp + 4);
        uint4 p;
        p.x = pk_bf16(f0.x, f0.y); p.y = pk_bf16(f0.z, f0.w);
        p.z = pk_bf16(f1.x, f1.y); p.w = pk_bf16(f1.z, f1.w);
        *reinterpret_cast<uint4*>(&hsB[row][k0]) = p;
    }
    if (cg == 0) {
        for (int idx = t; idx < 16 * DD; idx += 256) {
            const int row = r0 + (idx >> 7), d = idx & (DD - 1);
            if (row < ROWS)
                nt_store(&GhP[(size_t)row * 512 + d * 4 + 3],
                         f2bf(h[(size_t)row * DD + d]));
        }
    }
    __syncthreads();

    const int wv = t >> 6, l = t & 63;
    const int colhalf = wv >> 1, khalf = wv & 1;
    const int lcol = l & 15, lk = l >> 4;      // col-in-tile, k-group

    const int  cc2 = cg * 32 + colhalf * 16 + lcol;   // 0..767
    const bool isI = cc2 < C3;
    const int  cc  = isI ? cc2 : cc2 - C3;
    const float* __restrict__ W = isI ? Wi : Wh;

    float4x acc = {0.f, 0.f, 0.f, 0.f};
#pragma unroll
    for (int ks = 0; ks < 2; ++ks) {
        const int kbase = khalf * 64 + ks * 32 + lk * 8;
        const short8x a = *reinterpret_cast<const short8x*>(&hsB[lcol][kbase]);
        const float* wp = W + (size_t)cc * DD + kbase;
        const float4 g0 = *reinterpret_cast<const float4*>(wp);
        const float4 g1 = *reinterpret_cast<const float4*>(wp + 4);
        union { unsigned int u[4]; short8x s; } bu;
        bu.u[0] = pk_bf16(g0.x, g0.y); bu.u[1] = pk_bf16(g0.z, g0.w);
        bu.u[2] = pk_bf16(g1.x, g1.y); bu.u[3] = pk_bf16(g1.z, g1.w);
        acc = __builtin_amdgcn_mfma_f32_16x16x32_bf16(a, bu.s, acc, 0, 0, 0);
    }

    if (khalf == 1) {
#pragma unroll
        for (int r = 0; r < 4; ++r) sacc[colhalf][l][r] = acc[r];
    }
    __syncthreads();
    if (khalf == 0) {
        // Epilogue: C layout col=lane&15, row=(lane>>4)*4+reg  [m89-verified]
        const int   gate  = cc >> 7, d = cc & (DD - 1);
        const float scale = (gate == 2) ? 2.0f * NL2E : NL2E;
        const float bv    = (isI ? bi : bh)[cc];
        unsigned short* __restrict__ G = isI ? GiP : GhP;
#pragma unroll
        for (int r = 0; r < 4; ++r) {
            const int row = r0 + lk * 4 + r;
            if (row < ROWS) {
                float v = (acc[r] + sacc[colhalf][l][r] + bv) * scale;
                if (gate != 2) v = __builtin_amdgcn_exp2f(v);   // pre-exp r/z
                nt_store(&G[(size_t)row * 512 + d * 4 + gate], f2bf(v));
            }
        }
    }
}

// Phase kernel  [R19 verbatim]
template<int XC, int WRITE_OUT>
__global__ __launch_bounds__(512, 4) void phase_kernel(
    const float* __restrict__ hin,
    const int* __restrict__ parent, const int* __restrict__ child,
    const unsigned short* __restrict__ GiP, const unsigned short* __restrict__ GhP,
    float* __restrict__ hout,
    const int* __restrict__ tgt, float* __restrict__ out) {
    const int bj = blockIdx.x;          // 0..1023
    const int t  = threadIdx.x;
    const int b  = bj >> 7, j = bj & (NN - 1);
    const size_t base = (size_t)b * NN * NN + j;          // + i*NN

    __shared__ int   pcs[2 * NN];       // interleaved {p,c} pairs
    __shared__ float sacc[8][DD];       // 4 KB
    if (t < NN)            pcs[2 * t]            = parent[base + (size_t)t * NN];
    else if (t < 2 * NN)   pcs[2 * (t - NN) + 1] = child [base + (size_t)(t - NN) * NN];
    __syncthreads();

    const int w = t >> 6, l = t & 63;
    const int d0 = l * 2;               // d-pair (d0, d0+1)
    float acc0 = 0.0f, acc1 = 0.0f;
#pragma unroll 4
    for (int it = 0; it < 16; ++it) {
        const int  i  = w + it * 8;
        const int2 pc = *reinterpret_cast<const int2*>(&pcs[2 * i]);
        const int  xi = XC ? pc.y : pc.x;
        const int  hi = XC ? pc.x : pc.y;
        const uint4 ux = *reinterpret_cast<const uint4*>(GiP + (size_t)xi * 512 + d0 * 4);
        const uint4 uh = *reinterpret_cast<const uint4*>(GhP + (size_t)hi * 512 + d0 * 4);
        {
            const float Eir = __uint_as_float(ux.x << 16);
            const float Eiz = __uint_as_float(ux.x & 0xffff0000u);
            const float ins = __uint_as_float(ux.y << 16);
            const float Ehr = __uint_as_float(uh.x << 16);
            const float Ehz = __uint_as_float(uh.x & 0xffff0000u);
            const float hns = __uint_as_float(uh.y << 16);
            const float hv  = __uint_as_float(uh.y & 0xffff0000u);
            const float r = __builtin_amdgcn_rcpf(1.0f + Eir * Ehr);
            const float z = __builtin_amdgcn_rcpf(1.0f + Eiz * Ehz);
            const float q = __builtin_amdgcn_rcpf(1.0f + __builtin_amdgcn_exp2f(ins + r * hns));
            const float n = 2.0f * q - 1.0f;
            acc0 += n + z * (hv - n);
        }
        {
            const float Eir = __uint_as_float(ux.z << 16);
            const float Eiz = __uint_as_float(ux.z & 0xffff0000u);
            const float ins = __uint_as_float(ux.w << 16);
            const float Ehr = __uint_as_float(uh.z << 16);
            const float Ehz = __uint_as_float(uh.z & 0xffff0000u);
            const float hns = __uint_as_float(uh.w << 16);
            const float hv  = __uint_as_float(uh.w & 0xffff0000u);
            const float r = __builtin_amdgcn_rcpf(1.0f + Eir * Ehr);
            const float z = __builtin_amdgcn_rcpf(1.0f + Eiz * Ehz);
            const float q = __builtin_amdgcn_rcpf(1.0f + __builtin_amdgcn_exp2f(ins + r * hns));
            const float n = 2.0f * q - 1.0f;
            acc1 += n + z * (hv - n);
        }
    }
    sacc[w][d0] = acc0;
    sacc[w][d0 + 1] = acc1;
    __syncthreads();

    if (t < DD) {
        const int d = t;
        float v = sacc[0][d];
#pragma unroll
        for (int ww = 1; ww < 8; ++ww) v += sacc[ww][d];
        const int   row = 1 + bj;
        const float res = hin[(size_t)row * DD + d] + v;
        if (WRITE_OUT) {
#pragma unroll
            for (int bb = 0; bb < BB; ++bb)
                if (tgt[bb] == row) out[bb * DD + d] = res;
        } else {
            nt_store(&hout[(size_t)row * DD + d], res);   // read cross-XCD by gtab2
        }
    } else if (t < 2 * DD && bj == 0 && !WRITE_OUT) {
        nt_store(&hout[t - DD], hin[t - DD]);   // row 0 unchanged (tgt >= 1)
    }
}

extern "C" void kernel_launch(void* const* d_in, const int* in_sizes, int n_in,
                              void* d_out, int out_size, void* d_ws, size_t ws_size,
                              hipStream_t stream) {
    const float* hidden = (const float*)d_in[0];
    const int*   parent = (const int*)d_in[1];
    const int*   child  = (const int*)d_in[2];
    const int*   tgt    = (const int*)d_in[3];
    const float* Wif    = (const float*)d_in[4];
    const float* Whf    = (const float*)d_in[5];
    const float* bif    = (const float*)d_in[6];
    const float* bhf    = (const float*)d_in[7];
    const float* Wib    = (const float*)d_in[8];
    const float* Whb    = (const float*)d_in[9];
    const float* bib    = (const float*)d_in[10];
    const float* bhb    = (const float*)d_in[11];

    char* ws = (char*)d_ws;
    unsigned short* GiP = (unsigned short*)(ws);                  // 1025*512 bf16
    unsigned short* GhP = (unsigned short*)(ws + 1049600);        // 1025*512 bf16
    float*          h1  = (float*)(ws + 2099200);                 // 1025*128 f32
    float*          out = (float*)d_out;

    // Phase 1: bwd weights, x = child, h = parent
    gtab_kernel<<<1560, 256, 0, stream>>>(hidden, Wib, Whb, bib, bhb, GiP, GhP);
    phase_kernel<1, 0><<<BB * NN, 512, 0, stream>>>(hidden, parent, child, GiP, GhP, h1, nullptr, nullptr);
    // Phase 2: fwd weights, x = parent, h = child; tgt gather fused
    gtab_kernel<<<1560, 256, 0, stream>>>(h1, Wif, Whf, bif, bhf, GiP, GhP);
    phase_kernel<0, 1><<<BB * NN, 512, 0, stream>>>(h1, parent, child, GiP, GhP, nullptr, tgt, out);
}